// Round 11
// baseline (55087.463 us; speedup 1.0000x reference)
//
#include <hip/hip_runtime.h>

typedef __attribute__((ext_vector_type(8))) short short8;
typedef __attribute__((ext_vector_type(4))) float f32x4;

#define NTHR 512
#define NT2  256
#define BSZ 128
#define HID 1024
#define INP 256
#define LAT 512
#define OUTD 256

// ---- bf16 element offsets in ws ----
#define O_WIH0 0u
#define O_WHH0 1048576u
#define O_WIH1 5242880u
#define O_WHH1 9437184u
#define O_WFC1 13631488u
#define O_WFC2 14680064u
#define O_WGH  14942208u      /* left half, [1024][1024] */
#define O_WGC  15990784u      /* left half, [1024][1024] */
#define O_ZB   17039360u
#define O_XB   17104896u
#define O_HZ   17137664u
#define O_CZB  17268736u
#define O_H0N  17399808u
#define O_H1N  17530880u
#define O_H0F  17661952u
#define O_H1F  17793024u
#define O_C0NB 17924096u
#define O_C1NB 18055168u
#define O_RB   18186240u
#define BF_END 18317312u
#define F32BASE (2u*BF_END)
#define OF_GHZ 0u
#define OF_GCZ 131072u
#define OF_CZ  262144u
#define OF_C0N 393216u
#define OF_C1N 524288u
#define OF_C0F 655360u
#define OF_C1F 786432u

__device__ __forceinline__ unsigned short f2bf(float x) {
  union { float f; unsigned u; } v; v.f = x;
  return (unsigned short)((v.u + 0x7fffu + ((v.u >> 16) & 1u)) >> 16);
}
__device__ __forceinline__ float bf2f(unsigned short h) {
  union { unsigned u; float f; } v; v.u = ((unsigned)h) << 16;
  return v.f;
}
__device__ __forceinline__ float sigm(float x) { return 1.f / (1.f + __expf(-x)); }
__device__ __forceinline__ float ftanh(float x) { return 1.f - 2.f / (__expf(2.f * x) + 1.f); }
__device__ __forceinline__ unsigned packbf(float a, float b) {
  return (unsigned)f2bf(a) | ((unsigned)f2bf(b) << 16);
}
__device__ __forceinline__ short8 ldwf(const float* s) {
  const float4* p = (const float4*)s;
  float4 x = p[0], y = p[1];
  short8 r;
  r[0]=(short)f2bf(x.x); r[1]=(short)f2bf(x.y); r[2]=(short)f2bf(x.z); r[3]=(short)f2bf(x.w);
  r[4]=(short)f2bf(y.x); r[5]=(short)f2bf(y.y); r[6]=(short)f2bf(y.z); r[7]=(short)f2bf(y.w);
  return r;
}

__device__ __forceinline__ void conv4(const float* __restrict__ s, unsigned short* __restrict__ d,
                                      int n4, int gtid, int gsz) {
  const float4* s4 = (const float4*)s;
  ushort4* d4 = (ushort4*)d;
  for (int i = gtid; i < n4; i += gsz) {
    float4 v = s4[i];
    ushort4 o; o.x=f2bf(v.x); o.y=f2bf(v.y); o.z=f2bf(v.z); o.w=f2bf(v.w);
    d4[i] = o;
  }
}
__device__ __forceinline__ void convHalf(const float* __restrict__ s, unsigned short* __restrict__ d,
                                         int gtid, int gsz) {
  for (int i = gtid; i < (1024*1024)/4; i += gsz) {
    int row = i >> 8, c4 = (i & 255) * 4;
    float4 v = *(const float4*)(s + (size_t)row*2048 + c4);
    ushort4 o; o.x=f2bf(v.x); o.y=f2bf(v.y); o.z=f2bf(v.z); o.w=f2bf(v.w);
    *(ushort4*)(d + (size_t)row*1024 + c4) = o;
  }
}

template<int NI>
__device__ __forceinline__ f32x4 mmK(const unsigned short* a, const unsigned short* w, f32x4 acc) {
#pragma unroll
  for (int i = 0; i < NI; ++i) {
    short8 af = *(const short8*)(a + 32 * i);
    short8 bf = *(const short8*)(w + 32 * i);
    acc = __builtin_amdgcn_mfma_f32_16x16x32_bf16(af, bf, acc, 0, 0, 0);
  }
  return acc;
}
template<int NI>
__device__ __forceinline__ f32x4 mmKf(const unsigned short* a, const float* w, f32x4 acc) {
#pragma unroll
  for (int i = 0; i < NI; ++i) {
    short8 af = *(const short8*)(a + 32 * i);
    short8 bf = ldwf(w + 32 * i);
    acc = __builtin_amdgcn_mfma_f32_16x16x32_bf16(af, bf, acc, 0, 0, 0);
  }
  return acc;
}

__device__ __forceinline__ void dumpw(float* gat, f32x4 acc, int kh, int cg, int lane) {
  int lm = lane & 15, lq = lane >> 4;
#pragma unroll
  for (int j = 0; j < 4; ++j)
    gat[(kh * 16 + lq * 4 + j) * 64 + 16 * cg + lm] = acc[j];
}
__device__ __forceinline__ float gs(const float* gat, int row, int col) {
  return gat[row * 64 + col] + gat[1024 + row * 64 + col];
}

// touch one 8 KB contiguous region: 64 lanes x 4B @128B stride -> 64 line-fills in flight
__device__ __forceinline__ float touch8k(const unsigned short* p, int lane) {
  return ((const float*)p)[lane * 32];
}
// touch one 2 KB contiguous region (row len 512B x 4 rows)
__device__ __forceinline__ float touch2k(const unsigned short* p, int lane) {
  return ((const float*)p)[lane * 8];
}
__device__ __forceinline__ void sink(float v) { asm volatile("" :: "v"(v)); }

// ---- prologue: stage weights + z to bf16, init x ----
__global__ __launch_bounds__(256)
void k_conv(const float* __restrict__ z, const float* __restrict__ stok,
            const float* __restrict__ W_ih0, const float* __restrict__ W_hh0,
            const float* __restrict__ W_ih1, const float* __restrict__ W_hh1,
            const float* __restrict__ W_fc1, const float* __restrict__ W_fc2,
            const float* __restrict__ Wg_h, const float* __restrict__ Wg_c,
            unsigned char* __restrict__ ws) {
  int gtid = (int)blockIdx.x * 256 + (int)threadIdx.x, gsz = (int)gridDim.x * 256;
  unsigned short* bfb = (unsigned short*)ws;
  conv4(z,     bfb + O_ZB,   (BSZ*LAT)/4, gtid, gsz);
  conv4(W_ih0, bfb + O_WIH0, 1048576/4, gtid, gsz);
  conv4(W_hh0, bfb + O_WHH0, 4194304/4, gtid, gsz);
  conv4(W_ih1, bfb + O_WIH1, 4194304/4, gtid, gsz);
  conv4(W_hh1, bfb + O_WHH1, 4194304/4, gtid, gsz);
  conv4(W_fc1, bfb + O_WFC1, 1048576/4, gtid, gsz);
  conv4(W_fc2, bfb + O_WFC2, 262144/4, gtid, gsz);
  convHalf(Wg_h, bfb + O_WGH, gtid, gsz);
  convHalf(Wg_c, bfb + O_WGC, gtid, gsz);
  for (int i = gtid; i < BSZ * INP; i += gsz) (bfb + O_XB)[i] = f2bf(stok[i & (INP - 1)]);
}

// ---- prologue: h_z / c_z ----
__global__ __launch_bounds__(NTHR)
void k_phb(const float* __restrict__ W_lh, const float* __restrict__ b_lh,
           const float* __restrict__ W_lc, const float* __restrict__ b_lc,
           unsigned char* __restrict__ ws) {
  __shared__ float gat[2048];
  const int b=(int)blockIdx.x, tid=(int)threadIdx.x;
  const int lane=tid&63, wave=tid>>6;
  const int lm=lane&15, lq8=(lane>>4)*8;
  const int cg=wave&3, kh=wave>>2;
  const int ct=8*((b>>3)&7)+(b&7);
  const int R0=(b>>6)*16;
  unsigned short* bfb=(unsigned short*)ws;
  float* f32b=(float*)(ws+F32BASE);
  if (ct >= 32) return;
  const float* Wf = (ct < 16) ? W_lh : W_lc;
  int jb = 64 * (ct & 15) + 16 * cg + lm;
  f32x4 acc = {};
  acc = mmKf<8>(bfb + O_ZB + (size_t)(R0 + lm) * LAT + kh * 256 + lq8,
                Wf + (size_t)jb * LAT + kh * 256 + lq8, acc);
  dumpw(gat, acc, kh, cg, lane);
  __syncthreads();
  int prow = tid >> 5, cp2 = 2 * (tid & 31);
  int j0 = 64 * (ct & 15) + cp2;
  size_t gi0 = (size_t)(R0 + prow) * HID + j0;
  if (ct < 16) {
    float v0 = ftanh(gs(gat, prow, cp2) + b_lh[j0]);
    float v1 = ftanh(gs(gat, prow, cp2 + 1) + b_lh[j0 + 1]);
    unsigned pk = packbf(v0, v1);
    *(unsigned*)(bfb + O_HZ + gi0) = pk;
    *(unsigned*)(bfb + O_H0F + gi0) = pk;
    *(unsigned*)(bfb + O_H1F + gi0) = pk;
  } else {
    float v0 = ftanh(gs(gat, prow, cp2) + b_lc[j0]);
    float v1 = ftanh(gs(gat, prow, cp2 + 1) + b_lc[j0 + 1]);
    *(unsigned*)(bfb + O_CZB + gi0) = packbf(v0, v1);
    float2 vv; vv.x = v0; vv.y = v1;
    *(float2*)(f32b + OF_CZ + gi0) = vv;
    *(float2*)(f32b + OF_C0F + gi0) = vv;
    *(float2*)(f32b + OF_C1F + gi0) = vv;
  }
}

// ---- prologue: Ghz / Gcz ----
__global__ __launch_bounds__(NTHR)
void k_phc(const float* __restrict__ Wg_h, const float* __restrict__ bg_h,
           const float* __restrict__ Wg_c, const float* __restrict__ bg_c,
           unsigned char* __restrict__ ws) {
  __shared__ float gat[2048];
  const int b=(int)blockIdx.x, tid=(int)threadIdx.x;
  const int lane=tid&63, wave=tid>>6;
  const int lm=lane&15, lq8=(lane>>4)*8;
  const int cg=wave&3, kh=wave>>2;
  const int ct=8*((b>>3)&7)+(b&7);
  const int R0=(b>>6)*16;
  unsigned short* bfb=(unsigned short*)ws;
  float* f32b=(float*)(ws+F32BASE);
  if (ct >= 32) return;
  const unsigned short* A = (ct < 16) ? bfb + O_HZ : bfb + O_CZB;
  const float* Wf = (ct < 16) ? Wg_h : Wg_c;
  int jb = 64 * (ct & 15) + 16 * cg + lm;
  f32x4 acc = {};
  acc = mmKf<16>(A + (size_t)(R0 + lm) * HID + kh * 512 + lq8,
                 Wf + (size_t)jb * (2 * HID) + HID + kh * 512 + lq8, acc);
  dumpw(gat, acc, kh, cg, lane);
  __syncthreads();
  int prow = tid >> 5, cp2 = 2 * (tid & 31);
  int j0 = 64 * (ct & 15) + cp2;
  const float* bg = (ct < 16) ? bg_h : bg_c;
  float* G = (ct < 16) ? f32b + OF_GHZ : f32b + OF_GCZ;
  float2 vv;
  vv.x = gs(gat, prow, cp2) + bg[j0];
  vv.y = gs(gat, prow, cp2 + 1) + bg[j0 + 1];
  *(float2*)(G + (size_t)(R0 + prow) * HID + j0) = vv;
}

// ======== steady-state: per-wave 16x16 full-K tiles, touch-prefetch, no barriers ========

// ---- A: gates0 = x@W_ih0^T + h0f@W_hh0^T -> h0n, c0n ----
__global__ __launch_bounds__(NT2)
void k_p1(const float* __restrict__ bih, const float* __restrict__ bhh,
          unsigned char* __restrict__ ws) {
  __shared__ float gat[4 * 272];
  unsigned short* bfb = (unsigned short*)ws;
  float* f32b = (float*)(ws + F32BASE);
  const int b = (int)blockIdx.x, tid = (int)threadIdx.x;
  const int lane = tid & 63, wave = tid >> 6;
  const int lm = lane & 15, lq8 = (lane >> 4) * 8;
  const int cg = b & 255, h = b >> 8;
  const int R0 = (4 * h + wave) * 16;
  const int U0 = 4 * cg;
  const int wrow = (lm >> 2) * HID + U0 + (lm & 3);
  // touch-prefetch: weight + activation line-fills, deep parallelism, no consumers
  {
    float d = 0.f;
#pragma unroll
    for (int g = 0; g < 4; ++g) {
      d += touch8k(bfb + O_WHH0 + (size_t)(g * 1024 + U0) * HID, lane);
      d += touch2k(bfb + O_WIH0 + (size_t)(g * 1024 + U0) * INP, lane);
    }
    d += touch8k(bfb + O_XB + (size_t)R0 * INP, lane);   // 16 rows x 512B = 8KB
#pragma unroll
    for (int q = 0; q < 4; ++q)
      d += ((const float*)(bfb + O_H0F + (size_t)R0 * HID))[q * 2048 + lane * 32];
    sink(d);
  }
  const int erow = lane >> 2, edu = lane & 3;
  const int eu = U0 + edu;
  const size_t egix = (size_t)(R0 + erow) * HID + eu;
  float cprev = (f32b + OF_C0F)[egix];
  float ebi = bih[eu] + bhh[eu];
  float ebf = bih[HID + eu] + bhh[HID + eu];
  float ebg = bih[2 * HID + eu] + bhh[2 * HID + eu];
  float ebo = bih[3 * HID + eu] + bhh[3 * HID + eu];

  f32x4 acc = {};
  acc = mmK<8>(bfb + O_XB + (size_t)(R0 + lm) * INP + lq8,
               bfb + O_WIH0 + (size_t)wrow * INP + lq8, acc);
  acc = mmK<32>(bfb + O_H0F + (size_t)(R0 + lm) * HID + lq8,
                bfb + O_WHH0 + (size_t)wrow * HID + lq8, acc);

  float* g = gat + wave * 272;
  const int wr = (lane >> 4) * 4;
#pragma unroll
  for (int j = 0; j < 4; ++j) g[(wr + j) * 17 + lm] = acc[j];
  float s_i = g[erow * 17 + edu];
  float s_f = g[erow * 17 + 4 + edu];
  float s_g = g[erow * 17 + 8 + edu];
  float s_o = g[erow * 17 + 12 + edu];
  float gi_ = sigm(s_i + ebi), gf_ = sigm(s_f + ebf);
  float gg_ = ftanh(s_g + ebg), go_ = sigm(s_o + ebo);
  float cn = gf_ * cprev + gi_ * gg_;
  (bfb + O_H0N)[egix] = f2bf(go_ * ftanh(cn));
  (f32b + OF_C0N)[egix] = cn;
  (bfb + O_C0NB)[egix] = f2bf(cn);
}

// ---- B: gates1 = h0n@W_ih1^T + h1f@W_hh1^T -> h1n, c1n ----
__global__ __launch_bounds__(NT2)
void k_p2(const float* __restrict__ bih, const float* __restrict__ bhh,
          unsigned char* __restrict__ ws) {
  __shared__ float gat[4 * 272];
  unsigned short* bfb = (unsigned short*)ws;
  float* f32b = (float*)(ws + F32BASE);
  const int b = (int)blockIdx.x, tid = (int)threadIdx.x;
  const int lane = tid & 63, wave = tid >> 6;
  const int lm = lane & 15, lq8 = (lane >> 4) * 8;
  const int cg = b & 255, h = b >> 8;
  const int R0 = (4 * h + wave) * 16;
  const int U0 = 4 * cg;
  const int wrow = (lm >> 2) * HID + U0 + (lm & 3);
  {
    float d = 0.f;
#pragma unroll
    for (int g = 0; g < 4; ++g) {
      d += touch8k(bfb + O_WIH1 + (size_t)(g * 1024 + U0) * HID, lane);
      d += touch8k(bfb + O_WHH1 + (size_t)(g * 1024 + U0) * HID, lane);
    }
#pragma unroll
    for (int q = 0; q < 4; ++q) {
      d += ((const float*)(bfb + O_H0N + (size_t)R0 * HID))[q * 2048 + lane * 32];
      d += ((const float*)(bfb + O_H1F + (size_t)R0 * HID))[q * 2048 + lane * 32];
    }
    sink(d);
  }
  const int erow = lane >> 2, edu = lane & 3;
  const int eu = U0 + edu;
  const size_t egix = (size_t)(R0 + erow) * HID + eu;
  float cprev = (f32b + OF_C1F)[egix];
  float ebi = bih[eu] + bhh[eu];
  float ebf = bih[HID + eu] + bhh[HID + eu];
  float ebg = bih[2 * HID + eu] + bhh[2 * HID + eu];
  float ebo = bih[3 * HID + eu] + bhh[3 * HID + eu];

  f32x4 acc = {};
  acc = mmK<32>(bfb + O_H0N + (size_t)(R0 + lm) * HID + lq8,
                bfb + O_WIH1 + (size_t)wrow * HID + lq8, acc);
  acc = mmK<32>(bfb + O_H1F + (size_t)(R0 + lm) * HID + lq8,
                bfb + O_WHH1 + (size_t)wrow * HID + lq8, acc);

  float* g = gat + wave * 272;
  const int wr = (lane >> 4) * 4;
#pragma unroll
  for (int j = 0; j < 4; ++j) g[(wr + j) * 17 + lm] = acc[j];
  float s_i = g[erow * 17 + edu];
  float s_f = g[erow * 17 + 4 + edu];
  float s_g = g[erow * 17 + 8 + edu];
  float s_o = g[erow * 17 + 12 + edu];
  float gi_ = sigm(s_i + ebi), gf_ = sigm(s_f + ebf);
  float gg_ = ftanh(s_g + ebg), go_ = sigm(s_o + ebo);
  float cn = gf_ * cprev + gi_ * gg_;
  (bfb + O_H1N)[egix] = f2bf(go_ * ftanh(cn));
  (f32b + OF_C1N)[egix] = cn;
  (bfb + O_C1NB)[egix] = f2bf(cn);
}

// ---- C': fc1 | gh0 | gh1 | gc0 | gc1 (WGH/WGC each read once) ----
__global__ __launch_bounds__(NT2)
void k_p3(const float* __restrict__ bfc1, unsigned char* __restrict__ ws) {
  unsigned short* bfb = (unsigned short*)ws;
  float* f32b = (float*)(ws + F32BASE);
  const int b = (int)blockIdx.x, tid = (int)threadIdx.x;
  const int lane = tid & 63, wave = tid >> 6;
  const int lm = lane & 15, lq8 = (lane >> 4) * 8;
  const int h = b / 320, t_ = b - 320 * h;   // role stride 64, h stride 320: XCD = c%8
  const int role = t_ >> 6;                  // 0 fc1, 1 gh0, 2 gh1, 3 gc0, 4 gc1
  const int c0 = (t_ & 63) * 16;
  const int R0 = (4 * h + wave) * 16;
  const unsigned short* A = (role == 0) ? bfb + O_H1N
                          : (role == 1) ? bfb + O_H0N
                          : (role == 2) ? bfb + O_H1N
                          : (role == 3) ? bfb + O_C0NB : bfb + O_C1NB;
  const unsigned short* W = (role == 0) ? bfb + O_WFC1
                          : (role <= 2) ? bfb + O_WGH : bfb + O_WGC;
  {
    float d = 0.f;
#pragma unroll
    for (int q = 0; q < 4; ++q) {
      d += ((const float*)(W + (size_t)c0 * HID))[q * 2048 + lane * 32];
      d += ((const float*)(A + (size_t)R0 * HID))[q * 2048 + lane * 32];
    }
    sink(d);
  }
  const int j = c0 + lm;
  f32x4 acc = {};
  acc = mmK<32>(A + (size_t)(R0 + lm) * HID + lq8,
                W + (size_t)j * HID + lq8, acc);
  const int wr = (lane >> 4) * 4;
#pragma unroll
  for (int jj = 0; jj < 4; ++jj) {
    const int row = wr + jj;
    const size_t gi0 = (size_t)(R0 + row) * HID + c0 + lm;
    float s = acc[jj];
    if (role == 0) {
      float v = s + bfc1[c0 + lm];
      (bfb + O_RB)[gi0] = f2bf(v > 0.f ? v : 0.f);
    } else if (role == 1 || role == 2) {
      const unsigned short* Hn = (role == 1) ? bfb + O_H0N : bfb + O_H1N;
      unsigned short* Hf = (role == 1) ? bfb + O_H0F : bfb + O_H1F;
      float g0 = sigm(s + (f32b + OF_GHZ)[gi0]);
      float n0 = g0 * bf2f(Hn[gi0]) + (1.f - g0) * bf2f((bfb + O_HZ)[gi0]);
      Hf[gi0] = f2bf(n0);
    } else {
      const float* Cn = (role == 3) ? f32b + OF_C0N : f32b + OF_C1N;
      float* Cf = (role == 3) ? f32b + OF_C0F : f32b + OF_C1F;
      float g0 = sigm(s + (f32b + OF_GCZ)[gi0]);
      Cf[gi0] = g0 * Cn[gi0] + (1.f - g0) * (f32b + OF_CZ)[gi0];
    }
  }
}

// ---- D: fc2(Rb)->y_t, x_{t+1} (tiny, 32 blocks) ----
__global__ __launch_bounds__(NT2)
void k_p4(const float* __restrict__ bfc2, float* __restrict__ out, int t, int T,
          unsigned char* __restrict__ ws) {
  unsigned short* bfb = (unsigned short*)ws;
  const int b = (int)blockIdx.x, tid = (int)threadIdx.x;
  const int lane = tid & 63, wave = tid >> 6;
  const int lm = lane & 15, lq8 = (lane >> 4) * 8;
  const int h = b >> 4, ct = b & 15;
  const int R0 = (4 * h + wave) * 16;
  const int c0 = ct * 16;
  {
    float d = 0.f;
#pragma unroll
    for (int q = 0; q < 4; ++q) {
      d += ((const float*)(bfb + O_WFC2 + (size_t)c0 * HID))[q * 2048 + lane * 32];
      d += ((const float*)(bfb + O_RB + (size_t)R0 * HID))[q * 2048 + lane * 32];
    }
    sink(d);
  }
  const int j = c0 + lm;
  f32x4 acc = {};
  acc = mmK<32>(bfb + O_RB + (size_t)(R0 + lm) * HID + lq8,
                bfb + O_WFC2 + (size_t)j * HID + lq8, acc);
  const int wr = (lane >> 4) * 4;
#pragma unroll
  for (int jj = 0; jj < 4; ++jj) {
    const int row = wr + jj;
    float v = acc[jj] + bfc2[c0 + lm];
    out[((size_t)(R0 + row) * T + t) * OUTD + c0 + lm] = v;
    (bfb + O_XB)[(size_t)(R0 + row) * INP + c0 + lm] = f2bf(v);
  }
}

extern "C" void kernel_launch(void* const* d_in, const int* in_sizes, int n_in,
                              void* d_out, int out_size, void* d_ws, size_t ws_size,
                              hipStream_t stream) {
  unsigned char* ws = (unsigned char*)d_ws;
  const float* z     = (const float*)d_in[0];
  const float* stok  = (const float*)d_in[2];
  const float* W_ih0 = (const float*)d_in[3];
  const float* W_hh0 = (const float*)d_in[4];
  const float* b_ih0 = (const float*)d_in[5];
  const float* b_hh0 = (const float*)d_in[6];
  const float* W_ih1 = (const float*)d_in[7];
  const float* W_hh1 = (const float*)d_in[8];
  const float* b_ih1 = (const float*)d_in[9];
  const float* b_hh1 = (const float*)d_in[10];
  const float* W_lh  = (const float*)d_in[11];
  const float* b_lh  = (const float*)d_in[12];
  const float* W_lc  = (const float*)d_in[13];
  const float* b_lc  = (const float*)d_in[14];
  const float* W_fc1 = (const float*)d_in[15];
  const float* b_fc1 = (const float*)d_in[16];
  const float* W_fc2 = (const float*)d_in[17];
  const float* b_fc2 = (const float*)d_in[18];
  const float* Wg_h  = (const float*)d_in[19];
  const float* bg_h  = (const float*)d_in[20];
  const float* Wg_c  = (const float*)d_in[21];
  const float* bg_c  = (const float*)d_in[22];

  const int T = out_size / (BSZ * OUTD);

  k_conv<<<dim3(2048), dim3(256), 0, stream>>>(z, stok, W_ih0, W_hh0, W_ih1, W_hh1,
                                               W_fc1, W_fc2, Wg_h, Wg_c, ws);
  k_phb<<<dim3(512), dim3(NTHR), 0, stream>>>(W_lh, b_lh, W_lc, b_lc, ws);
  k_phc<<<dim3(512), dim3(NTHR), 0, stream>>>(Wg_h, bg_h, Wg_c, bg_c, ws);

  for (int t = 0; t < T; ++t) {
    k_p1<<<dim3(512), dim3(NT2), 0, stream>>>(b_ih0, b_hh0, ws);
    k_p2<<<dim3(512), dim3(NT2), 0, stream>>>(b_ih1, b_hh1, ws);
    k_p3<<<dim3(640), dim3(NT2), 0, stream>>>(b_fc1, ws);
    k_p4<<<dim3(32), dim3(NT2), 0, stream>>>(b_fc2, (float*)d_out, t, T, ws);
  }
}

// Round 12
// 43355.838 us; speedup vs baseline: 1.2706x; 1.2706x over previous
//
#include <hip/hip_runtime.h>

typedef __attribute__((ext_vector_type(8))) short short8;
typedef __attribute__((ext_vector_type(4))) float f32x4;

#define NTHR 512
#define NT2  256
#define BSZ 128
#define HID 1024
#define INP 256
#define LAT 512
#define OUTD 256

// ---- bf16 element offsets in ws ----
#define O_WIH0 0u
#define O_WHH0 1048576u
#define O_WIH1 5242880u
#define O_WHH1 9437184u
#define O_WFC1 13631488u
#define O_WFC2 14680064u
#define O_WGH  14942208u      /* left half, [1024][1024] */
#define O_WGC  15990784u      /* left half, [1024][1024] */
#define O_ZB   17039360u
#define O_XB   17104896u
#define O_HZ   17137664u
#define O_CZB  17268736u
#define O_H0N  17399808u
#define O_H1N  17530880u
#define O_H0F  17661952u
#define O_H1F  17793024u
#define O_C0NB 17924096u
#define O_C1NB 18055168u
#define O_RB   18186240u
#define BF_END 18317312u
#define F32BASE (2u*BF_END)
#define OF_GHZ 0u
#define OF_GCZ 131072u
#define OF_CZ  262144u
#define OF_C0N 393216u
#define OF_C1N 524288u
#define OF_C0F 655360u
#define OF_C1F 786432u

__device__ __forceinline__ unsigned short f2bf(float x) {
  union { float f; unsigned u; } v; v.f = x;
  return (unsigned short)((v.u + 0x7fffu + ((v.u >> 16) & 1u)) >> 16);
}
__device__ __forceinline__ float bf2f(unsigned short h) {
  union { unsigned u; float f; } v; v.u = ((unsigned)h) << 16;
  return v.f;
}
__device__ __forceinline__ float sigm(float x) { return 1.f / (1.f + __expf(-x)); }
__device__ __forceinline__ float ftanh(float x) { return 1.f - 2.f / (__expf(2.f * x) + 1.f); }
__device__ __forceinline__ unsigned packbf(float a, float b) {
  return (unsigned)f2bf(a) | ((unsigned)f2bf(b) << 16);
}
__device__ __forceinline__ short8 ldwf(const float* s) {
  const float4* p = (const float4*)s;
  float4 x = p[0], y = p[1];
  short8 r;
  r[0]=(short)f2bf(x.x); r[1]=(short)f2bf(x.y); r[2]=(short)f2bf(x.z); r[3]=(short)f2bf(x.w);
  r[4]=(short)f2bf(y.x); r[5]=(short)f2bf(y.y); r[6]=(short)f2bf(y.z); r[7]=(short)f2bf(y.w);
  return r;
}

__device__ __forceinline__ void conv4(const float* __restrict__ s, unsigned short* __restrict__ d,
                                      int n4, int gtid, int gsz) {
  const float4* s4 = (const float4*)s;
  ushort4* d4 = (ushort4*)d;
  for (int i = gtid; i < n4; i += gsz) {
    float4 v = s4[i];
    ushort4 o; o.x=f2bf(v.x); o.y=f2bf(v.y); o.z=f2bf(v.z); o.w=f2bf(v.w);
    d4[i] = o;
  }
}
__device__ __forceinline__ void convHalf(const float* __restrict__ s, unsigned short* __restrict__ d,
                                         int gtid, int gsz) {
  for (int i = gtid; i < (1024*1024)/4; i += gsz) {
    int row = i >> 8, c4 = (i & 255) * 4;
    float4 v = *(const float4*)(s + (size_t)row*2048 + c4);
    ushort4 o; o.x=f2bf(v.x); o.y=f2bf(v.y); o.z=f2bf(v.z); o.w=f2bf(v.w);
    *(ushort4*)(d + (size_t)row*1024 + c4) = o;
  }
}

template<int NI>
__device__ __forceinline__ f32x4 mmK(const unsigned short* a, const unsigned short* w, f32x4 acc) {
#pragma unroll
  for (int i = 0; i < NI; ++i) {
    short8 af = *(const short8*)(a + 32 * i);
    short8 bf = *(const short8*)(w + 32 * i);
    acc = __builtin_amdgcn_mfma_f32_16x16x32_bf16(af, bf, acc, 0, 0, 0);
  }
  return acc;
}
template<int NI>
__device__ __forceinline__ f32x4 mmKf(const unsigned short* a, const float* w, f32x4 acc) {
#pragma unroll
  for (int i = 0; i < NI; ++i) {
    short8 af = *(const short8*)(a + 32 * i);
    short8 bf = ldwf(w + 32 * i);
    acc = __builtin_amdgcn_mfma_f32_16x16x32_bf16(af, bf, acc, 0, 0, 0);
  }
  return acc;
}

__device__ __forceinline__ void dumpw(float* gat, f32x4 acc, int kh, int cg, int lane) {
  int lm = lane & 15, lq = lane >> 4;
#pragma unroll
  for (int j = 0; j < 4; ++j)
    gat[(kh * 16 + lq * 4 + j) * 64 + 16 * cg + lm] = acc[j];
}
__device__ __forceinline__ float gs(const float* gat, int row, int col) {
  return gat[row * 64 + col] + gat[1024 + row * 64 + col];
}

// ---- prologue: stage weights + z to bf16, init x ----
__global__ __launch_bounds__(256)
void k_conv(const float* __restrict__ z, const float* __restrict__ stok,
            const float* __restrict__ W_ih0, const float* __restrict__ W_hh0,
            const float* __restrict__ W_ih1, const float* __restrict__ W_hh1,
            const float* __restrict__ W_fc1, const float* __restrict__ W_fc2,
            const float* __restrict__ Wg_h, const float* __restrict__ Wg_c,
            unsigned char* __restrict__ ws) {
  int gtid = (int)blockIdx.x * 256 + (int)threadIdx.x, gsz = (int)gridDim.x * 256;
  unsigned short* bfb = (unsigned short*)ws;
  conv4(z,     bfb + O_ZB,   (BSZ*LAT)/4, gtid, gsz);
  conv4(W_ih0, bfb + O_WIH0, 1048576/4, gtid, gsz);
  conv4(W_hh0, bfb + O_WHH0, 4194304/4, gtid, gsz);
  conv4(W_ih1, bfb + O_WIH1, 4194304/4, gtid, gsz);
  conv4(W_hh1, bfb + O_WHH1, 4194304/4, gtid, gsz);
  conv4(W_fc1, bfb + O_WFC1, 1048576/4, gtid, gsz);
  conv4(W_fc2, bfb + O_WFC2, 262144/4, gtid, gsz);
  convHalf(Wg_h, bfb + O_WGH, gtid, gsz);
  convHalf(Wg_c, bfb + O_WGC, gtid, gsz);
  for (int i = gtid; i < BSZ * INP; i += gsz) (bfb + O_XB)[i] = f2bf(stok[i & (INP - 1)]);
}

// ---- prologue: h_z / c_z ----
__global__ __launch_bounds__(NTHR)
void k_phb(const float* __restrict__ W_lh, const float* __restrict__ b_lh,
           const float* __restrict__ W_lc, const float* __restrict__ b_lc,
           unsigned char* __restrict__ ws) {
  __shared__ float gat[2048];
  const int b=(int)blockIdx.x, tid=(int)threadIdx.x;
  const int lane=tid&63, wave=tid>>6;
  const int lm=lane&15, lq8=(lane>>4)*8;
  const int cg=wave&3, kh=wave>>2;
  const int ct=8*((b>>3)&7)+(b&7);
  const int R0=(b>>6)*16;
  unsigned short* bfb=(unsigned short*)ws;
  float* f32b=(float*)(ws+F32BASE);
  if (ct >= 32) return;
  const float* Wf = (ct < 16) ? W_lh : W_lc;
  int jb = 64 * (ct & 15) + 16 * cg + lm;
  f32x4 acc = {};
  acc = mmKf<8>(bfb + O_ZB + (size_t)(R0 + lm) * LAT + kh * 256 + lq8,
                Wf + (size_t)jb * LAT + kh * 256 + lq8, acc);
  dumpw(gat, acc, kh, cg, lane);
  __syncthreads();
  int prow = tid >> 5, cp2 = 2 * (tid & 31);
  int j0 = 64 * (ct & 15) + cp2;
  size_t gi0 = (size_t)(R0 + prow) * HID + j0;
  if (ct < 16) {
    float v0 = ftanh(gs(gat, prow, cp2) + b_lh[j0]);
    float v1 = ftanh(gs(gat, prow, cp2 + 1) + b_lh[j0 + 1]);
    unsigned pk = packbf(v0, v1);
    *(unsigned*)(bfb + O_HZ + gi0) = pk;
    *(unsigned*)(bfb + O_H0F + gi0) = pk;
    *(unsigned*)(bfb + O_H1F + gi0) = pk;
  } else {
    float v0 = ftanh(gs(gat, prow, cp2) + b_lc[j0]);
    float v1 = ftanh(gs(gat, prow, cp2 + 1) + b_lc[j0 + 1]);
    *(unsigned*)(bfb + O_CZB + gi0) = packbf(v0, v1);
    float2 vv; vv.x = v0; vv.y = v1;
    *(float2*)(f32b + OF_CZ + gi0) = vv;
    *(float2*)(f32b + OF_C0F + gi0) = vv;
    *(float2*)(f32b + OF_C1F + gi0) = vv;
  }
}

// ---- prologue: Ghz / Gcz ----
__global__ __launch_bounds__(NTHR)
void k_phc(const float* __restrict__ Wg_h, const float* __restrict__ bg_h,
           const float* __restrict__ Wg_c, const float* __restrict__ bg_c,
           unsigned char* __restrict__ ws) {
  __shared__ float gat[2048];
  const int b=(int)blockIdx.x, tid=(int)threadIdx.x;
  const int lane=tid&63, wave=tid>>6;
  const int lm=lane&15, lq8=(lane>>4)*8;
  const int cg=wave&3, kh=wave>>2;
  const int ct=8*((b>>3)&7)+(b&7);
  const int R0=(b>>6)*16;
  unsigned short* bfb=(unsigned short*)ws;
  float* f32b=(float*)(ws+F32BASE);
  if (ct >= 32) return;
  const unsigned short* A = (ct < 16) ? bfb + O_HZ : bfb + O_CZB;
  const float* Wf = (ct < 16) ? Wg_h : Wg_c;
  int jb = 64 * (ct & 15) + 16 * cg + lm;
  f32x4 acc = {};
  acc = mmKf<16>(A + (size_t)(R0 + lm) * HID + kh * 512 + lq8,
                 Wf + (size_t)jb * (2 * HID) + HID + kh * 512 + lq8, acc);
  dumpw(gat, acc, kh, cg, lane);
  __syncthreads();
  int prow = tid >> 5, cp2 = 2 * (tid & 31);
  int j0 = 64 * (ct & 15) + cp2;
  const float* bg = (ct < 16) ? bg_h : bg_c;
  float* G = (ct < 16) ? f32b + OF_GHZ : f32b + OF_GCZ;
  float2 vv;
  vv.x = gs(gat, prow, cp2) + bg[j0];
  vv.y = gs(gat, prow, cp2 + 1) + bg[j0 + 1];
  *(float2*)(G + (size_t)(R0 + prow) * HID + j0) = vv;
}

// ======== steady-state: per-wave 16x16 full-K tiles, no barriers, no touches ========

// ---- A: gates0 = x@W_ih0^T + h0f@W_hh0^T -> h0n, c0n ----
__global__ __launch_bounds__(NT2)
void k_p1(const float* __restrict__ bih, const float* __restrict__ bhh,
          unsigned char* __restrict__ ws) {
  __shared__ float gat[4 * 272];
  unsigned short* bfb = (unsigned short*)ws;
  float* f32b = (float*)(ws + F32BASE);
  const int b = (int)blockIdx.x, tid = (int)threadIdx.x;
  const int lane = tid & 63, wave = tid >> 6;
  const int lm = lane & 15, lq8 = (lane >> 4) * 8;
  const int cg = b & 255, h = b >> 8;
  const int R0 = (4 * h + wave) * 16;
  const int U0 = 4 * cg;
  const int wrow = (lm >> 2) * HID + U0 + (lm & 3);
  const int erow = lane >> 2, edu = lane & 3;
  const int eu = U0 + edu;
  const size_t egix = (size_t)(R0 + erow) * HID + eu;
  float cprev = (f32b + OF_C0F)[egix];
  float ebi = bih[eu] + bhh[eu];
  float ebf = bih[HID + eu] + bhh[HID + eu];
  float ebg = bih[2 * HID + eu] + bhh[2 * HID + eu];
  float ebo = bih[3 * HID + eu] + bhh[3 * HID + eu];

  f32x4 acc = {};
  acc = mmK<8>(bfb + O_XB + (size_t)(R0 + lm) * INP + lq8,
               bfb + O_WIH0 + (size_t)wrow * INP + lq8, acc);
  acc = mmK<32>(bfb + O_H0F + (size_t)(R0 + lm) * HID + lq8,
                bfb + O_WHH0 + (size_t)wrow * HID + lq8, acc);

  float* g = gat + wave * 272;               // wave-private, no barrier needed
  const int wr = (lane >> 4) * 4;
#pragma unroll
  for (int j = 0; j < 4; ++j) g[(wr + j) * 17 + lm] = acc[j];
  float s_i = g[erow * 17 + edu];
  float s_f = g[erow * 17 + 4 + edu];
  float s_g = g[erow * 17 + 8 + edu];
  float s_o = g[erow * 17 + 12 + edu];
  float gi_ = sigm(s_i + ebi), gf_ = sigm(s_f + ebf);
  float gg_ = ftanh(s_g + ebg), go_ = sigm(s_o + ebo);
  float cn = gf_ * cprev + gi_ * gg_;
  (bfb + O_H0N)[egix] = f2bf(go_ * ftanh(cn));
  (f32b + OF_C0N)[egix] = cn;
  (bfb + O_C0NB)[egix] = f2bf(cn);
}

// ---- B: gates1 = h0n@W_ih1^T + h1f@W_hh1^T -> h1n, c1n ----
__global__ __launch_bounds__(NT2)
void k_p2(const float* __restrict__ bih, const float* __restrict__ bhh,
          unsigned char* __restrict__ ws) {
  __shared__ float gat[4 * 272];
  unsigned short* bfb = (unsigned short*)ws;
  float* f32b = (float*)(ws + F32BASE);
  const int b = (int)blockIdx.x, tid = (int)threadIdx.x;
  const int lane = tid & 63, wave = tid >> 6;
  const int lm = lane & 15, lq8 = (lane >> 4) * 8;
  const int cg = b & 255, h = b >> 8;
  const int R0 = (4 * h + wave) * 16;
  const int U0 = 4 * cg;
  const int wrow = (lm >> 2) * HID + U0 + (lm & 3);
  const int erow = lane >> 2, edu = lane & 3;
  const int eu = U0 + edu;
  const size_t egix = (size_t)(R0 + erow) * HID + eu;
  float cprev = (f32b + OF_C1F)[egix];
  float ebi = bih[eu] + bhh[eu];
  float ebf = bih[HID + eu] + bhh[HID + eu];
  float ebg = bih[2 * HID + eu] + bhh[2 * HID + eu];
  float ebo = bih[3 * HID + eu] + bhh[3 * HID + eu];

  f32x4 acc = {};
  acc = mmK<32>(bfb + O_H0N + (size_t)(R0 + lm) * HID + lq8,
                bfb + O_WIH1 + (size_t)wrow * HID + lq8, acc);
  acc = mmK<32>(bfb + O_H1F + (size_t)(R0 + lm) * HID + lq8,
                bfb + O_WHH1 + (size_t)wrow * HID + lq8, acc);

  float* g = gat + wave * 272;
  const int wr = (lane >> 4) * 4;
#pragma unroll
  for (int j = 0; j < 4; ++j) g[(wr + j) * 17 + lm] = acc[j];
  float s_i = g[erow * 17 + edu];
  float s_f = g[erow * 17 + 4 + edu];
  float s_g = g[erow * 17 + 8 + edu];
  float s_o = g[erow * 17 + 12 + edu];
  float gi_ = sigm(s_i + ebi), gf_ = sigm(s_f + ebf);
  float gg_ = ftanh(s_g + ebg), go_ = sigm(s_o + ebo);
  float cn = gf_ * cprev + gi_ * gg_;
  (bfb + O_H1N)[egix] = f2bf(go_ * ftanh(cn));
  (f32b + OF_C1N)[egix] = cn;
  (bfb + O_C1NB)[egix] = f2bf(cn);
}

// ---- C': fc1 | gh0 | gh1 | gc0 | gc1 (WGH/WGC each read once) ----
__global__ __launch_bounds__(NT2)
void k_p3(const float* __restrict__ bfc1, unsigned char* __restrict__ ws) {
  unsigned short* bfb = (unsigned short*)ws;
  float* f32b = (float*)(ws + F32BASE);
  const int b = (int)blockIdx.x, tid = (int)threadIdx.x;
  const int lane = tid & 63, wave = tid >> 6;
  const int lm = lane & 15, lq8 = (lane >> 4) * 8;
  const int h = b / 320, t_ = b - 320 * h;   // role stride 64: XCD = c%8 preserved
  const int role = t_ >> 6;                  // 0 fc1, 1 gh0, 2 gh1, 3 gc0, 4 gc1
  const int c0 = (t_ & 63) * 16;
  const int R0 = (4 * h + wave) * 16;
  const unsigned short* A = (role == 0) ? bfb + O_H1N
                          : (role == 1) ? bfb + O_H0N
                          : (role == 2) ? bfb + O_H1N
                          : (role == 3) ? bfb + O_C0NB : bfb + O_C1NB;
  const unsigned short* W = (role == 0) ? bfb + O_WFC1
                          : (role <= 2) ? bfb + O_WGH : bfb + O_WGC;
  const int j = c0 + lm;
  f32x4 acc = {};
  acc = mmK<32>(A + (size_t)(R0 + lm) * HID + lq8,
                W + (size_t)j * HID + lq8, acc);
  const int wr = (lane >> 4) * 4;
#pragma unroll
  for (int jj = 0; jj < 4; ++jj) {
    const int row = wr + jj;
    const size_t gi0 = (size_t)(R0 + row) * HID + c0 + lm;
    float s = acc[jj];
    if (role == 0) {
      float v = s + bfc1[c0 + lm];
      (bfb + O_RB)[gi0] = f2bf(v > 0.f ? v : 0.f);
    } else if (role == 1 || role == 2) {
      const unsigned short* Hn = (role == 1) ? bfb + O_H0N : bfb + O_H1N;
      unsigned short* Hf = (role == 1) ? bfb + O_H0F : bfb + O_H1F;
      float g0 = sigm(s + (f32b + OF_GHZ)[gi0]);
      float n0 = g0 * bf2f(Hn[gi0]) + (1.f - g0) * bf2f((bfb + O_HZ)[gi0]);
      Hf[gi0] = f2bf(n0);
    } else {
      const float* Cn = (role == 3) ? f32b + OF_C0N : f32b + OF_C1N;
      float* Cf = (role == 3) ? f32b + OF_C0F : f32b + OF_C1F;
      float g0 = sigm(s + (f32b + OF_GCZ)[gi0]);
      Cf[gi0] = g0 * Cn[gi0] + (1.f - g0) * (f32b + OF_CZ)[gi0];
    }
  }
}

// ---- D: fc2(Rb)->y_t, x_{t+1} (tiny, 32 blocks) ----
__global__ __launch_bounds__(NT2)
void k_p4(const float* __restrict__ bfc2, float* __restrict__ out, int t, int T,
          unsigned char* __restrict__ ws) {
  unsigned short* bfb = (unsigned short*)ws;
  const int b = (int)blockIdx.x, tid = (int)threadIdx.x;
  const int lane = tid & 63, wave = tid >> 6;
  const int lm = lane & 15, lq8 = (lane >> 4) * 8;
  const int h = b >> 4, ct = b & 15;
  const int R0 = (4 * h + wave) * 16;
  const int c0 = ct * 16;
  const int j = c0 + lm;
  f32x4 acc = {};
  acc = mmK<32>(bfb + O_RB + (size_t)(R0 + lm) * HID + lq8,
                bfb + O_WFC2 + (size_t)j * HID + lq8, acc);
  const int wr = (lane >> 4) * 4;
#pragma unroll
  for (int jj = 0; jj < 4; ++jj) {
    const int row = wr + jj;
    float v = acc[jj] + bfc2[c0 + lm];
    out[((size_t)(R0 + row) * T + t) * OUTD + c0 + lm] = v;
    (bfb + O_XB)[(size_t)(R0 + row) * INP + c0 + lm] = f2bf(v);
  }
}

extern "C" void kernel_launch(void* const* d_in, const int* in_sizes, int n_in,
                              void* d_out, int out_size, void* d_ws, size_t ws_size,
                              hipStream_t stream) {
  unsigned char* ws = (unsigned char*)d_ws;
  const float* z     = (const float*)d_in[0];
  const float* stok  = (const float*)d_in[2];
  const float* W_ih0 = (const float*)d_in[3];
  const float* W_hh0 = (const float*)d_in[4];
  const float* b_ih0 = (const float*)d_in[5];
  const float* b_hh0 = (const float*)d_in[6];
  const float* W_ih1 = (const float*)d_in[7];
  const float* W_hh1 = (const float*)d_in[8];
  const float* b_ih1 = (const float*)d_in[9];
  const float* b_hh1 = (const float*)d_in[10];
  const float* W_lh  = (const float*)d_in[11];
  const float* b_lh  = (const float*)d_in[12];
  const float* W_lc  = (const float*)d_in[13];
  const float* b_lc  = (const float*)d_in[14];
  const float* W_fc1 = (const float*)d_in[15];
  const float* b_fc1 = (const float*)d_in[16];
  const float* W_fc2 = (const float*)d_in[17];
  const float* b_fc2 = (const float*)d_in[18];
  const float* Wg_h  = (const float*)d_in[19];
  const float* bg_h  = (const float*)d_in[20];
  const float* Wg_c  = (const float*)d_in[21];
  const float* bg_c  = (const float*)d_in[22];

  const int T = out_size / (BSZ * OUTD);

  k_conv<<<dim3(2048), dim3(256), 0, stream>>>(z, stok, W_ih0, W_hh0, W_ih1, W_hh1,
                                               W_fc1, W_fc2, Wg_h, Wg_c, ws);
  k_phb<<<dim3(512), dim3(NTHR), 0, stream>>>(W_lh, b_lh, W_lc, b_lc, ws);
  k_phc<<<dim3(512), dim3(NTHR), 0, stream>>>(Wg_h, bg_h, Wg_c, bg_c, ws);

  for (int t = 0; t < T; ++t) {
    k_p1<<<dim3(512), dim3(NT2), 0, stream>>>(b_ih0, b_hh0, ws);
    k_p2<<<dim3(512), dim3(NT2), 0, stream>>>(b_ih1, b_hh1, ws);
    k_p3<<<dim3(640), dim3(NT2), 0, stream>>>(b_fc1, ws);
    k_p4<<<dim3(32), dim3(NT2), 0, stream>>>(b_fc2, (float*)d_out, t, T, ws);
  }
}

// Round 13
// 29179.401 us; speedup vs baseline: 1.8879x; 1.4858x over previous
//
#include <hip/hip_runtime.h>

typedef __attribute__((ext_vector_type(8))) short short8;
typedef __attribute__((ext_vector_type(4))) float f32x4;

#define NTHR 512
#define NT2  256
#define BSZ 128
#define HID 1024
#define INP 256
#define LAT 512
#define OUTD 256

// ---- bf16 element offsets in ws ----
#define O_WIH0 0u
#define O_WHH0 1048576u
#define O_WIH1 5242880u
#define O_WHH1 9437184u
#define O_WFC1 13631488u
#define O_WFC2 14680064u
#define O_WGH  14942208u      /* left half, [1024][1024] */
#define O_WGC  15990784u      /* left half, [1024][1024] */
#define O_ZB   17039360u
#define O_XB   17104896u
#define O_HZ   17137664u
#define O_CZB  17268736u
#define O_H0N  17399808u
#define O_H1N  17530880u
#define O_H0F  17661952u
#define O_H1F  17793024u
#define O_C0NB 17924096u
#define O_C1NB 18055168u
#define O_RB   18186240u
#define BF_END 18317312u
#define F32BASE (2u*BF_END)
#define OF_GHZ 0u
#define OF_GCZ 131072u
#define OF_CZ  262144u
#define OF_C0N 393216u
#define OF_C1N 524288u
#define OF_C0F 655360u
#define OF_C1F 786432u

typedef const __attribute__((address_space(1))) void* gas_t;
typedef __attribute__((address_space(3))) void* las_t;
// async 1KB DMA: 64 lanes x 16B; global src per-lane, LDS dst = uniform base + lane*16
#define GLL16(g, l) __builtin_amdgcn_global_load_lds((gas_t)(g), (las_t)(l), 16, 0, 0)

__device__ __forceinline__ unsigned short f2bf(float x) {
  union { float f; unsigned u; } v; v.f = x;
  return (unsigned short)((v.u + 0x7fffu + ((v.u >> 16) & 1u)) >> 16);
}
__device__ __forceinline__ float bf2f(unsigned short h) {
  union { unsigned u; float f; } v; v.u = ((unsigned)h) << 16;
  return v.f;
}
__device__ __forceinline__ float sigm(float x) { return 1.f / (1.f + __expf(-x)); }
__device__ __forceinline__ float ftanh(float x) { return 1.f - 2.f / (__expf(2.f * x) + 1.f); }
__device__ __forceinline__ unsigned packbf(float a, float b) {
  return (unsigned)f2bf(a) | ((unsigned)f2bf(b) << 16);
}
__device__ __forceinline__ short8 ldwf(const float* s) {
  const float4* p = (const float4*)s;
  float4 x = p[0], y = p[1];
  short8 r;
  r[0]=(short)f2bf(x.x); r[1]=(short)f2bf(x.y); r[2]=(short)f2bf(x.z); r[3]=(short)f2bf(x.w);
  r[4]=(short)f2bf(y.x); r[5]=(short)f2bf(y.y); r[6]=(short)f2bf(y.z); r[7]=(short)f2bf(y.w);
  return r;
}

__device__ __forceinline__ void conv4(const float* __restrict__ s, unsigned short* __restrict__ d,
                                      int n4, int gtid, int gsz) {
  const float4* s4 = (const float4*)s;
  ushort4* d4 = (ushort4*)d;
  for (int i = gtid; i < n4; i += gsz) {
    float4 v = s4[i];
    ushort4 o; o.x=f2bf(v.x); o.y=f2bf(v.y); o.z=f2bf(v.z); o.w=f2bf(v.w);
    d4[i] = o;
  }
}
__device__ __forceinline__ void convHalf(const float* __restrict__ s, unsigned short* __restrict__ d,
                                         int gtid, int gsz) {
  for (int i = gtid; i < (1024*1024)/4; i += gsz) {
    int row = i >> 8, c4 = (i & 255) * 4;
    float4 v = *(const float4*)(s + (size_t)row*2048 + c4);
    ushort4 o; o.x=f2bf(v.x); o.y=f2bf(v.y); o.z=f2bf(v.z); o.w=f2bf(v.w);
    *(ushort4*)(d + (size_t)row*1024 + c4) = o;
  }
}

template<int NI>
__device__ __forceinline__ f32x4 mmK(const unsigned short* a, const unsigned short* w, f32x4 acc) {
#pragma unroll
  for (int i = 0; i < NI; ++i) {
    short8 af = *(const short8*)(a + 32 * i);
    short8 bf = *(const short8*)(w + 32 * i);
    acc = __builtin_amdgcn_mfma_f32_16x16x32_bf16(af, bf, acc, 0, 0, 0);
  }
  return acc;
}
template<int NI>
__device__ __forceinline__ f32x4 mmKf(const unsigned short* a, const float* w, f32x4 acc) {
#pragma unroll
  for (int i = 0; i < NI; ++i) {
    short8 af = *(const short8*)(a + 32 * i);
    short8 bf = ldwf(w + 32 * i);
    acc = __builtin_amdgcn_mfma_f32_16x16x32_bf16(af, bf, acc, 0, 0, 0);
  }
  return acc;
}

__device__ __forceinline__ void dumpw(float* gat, f32x4 acc, int kh, int cg, int lane) {
  int lm = lane & 15, lq = lane >> 4;
#pragma unroll
  for (int j = 0; j < 4; ++j)
    gat[(kh * 16 + lq * 4 + j) * 64 + 16 * cg + lm] = acc[j];
}
__device__ __forceinline__ float gs(const float* gat, int row, int col) {
  return gat[row * 64 + col] + gat[1024 + row * 64 + col];
}

// ---- prologue: stage weights + z to bf16, init x ----
__global__ __launch_bounds__(256)
void k_conv(const float* __restrict__ z, const float* __restrict__ stok,
            const float* __restrict__ W_ih0, const float* __restrict__ W_hh0,
            const float* __restrict__ W_ih1, const float* __restrict__ W_hh1,
            const float* __restrict__ W_fc1, const float* __restrict__ W_fc2,
            const float* __restrict__ Wg_h, const float* __restrict__ Wg_c,
            unsigned char* __restrict__ ws) {
  int gtid = (int)blockIdx.x * 256 + (int)threadIdx.x, gsz = (int)gridDim.x * 256;
  unsigned short* bfb = (unsigned short*)ws;
  conv4(z,     bfb + O_ZB,   (BSZ*LAT)/4, gtid, gsz);
  conv4(W_ih0, bfb + O_WIH0, 1048576/4, gtid, gsz);
  conv4(W_hh0, bfb + O_WHH0, 4194304/4, gtid, gsz);
  conv4(W_ih1, bfb + O_WIH1, 4194304/4, gtid, gsz);
  conv4(W_hh1, bfb + O_WHH1, 4194304/4, gtid, gsz);
  conv4(W_fc1, bfb + O_WFC1, 1048576/4, gtid, gsz);
  conv4(W_fc2, bfb + O_WFC2, 262144/4, gtid, gsz);
  convHalf(Wg_h, bfb + O_WGH, gtid, gsz);
  convHalf(Wg_c, bfb + O_WGC, gtid, gsz);
  for (int i = gtid; i < BSZ * INP; i += gsz) (bfb + O_XB)[i] = f2bf(stok[i & (INP - 1)]);
}

// ---- prologue: h_z / c_z ----
__global__ __launch_bounds__(NTHR)
void k_phb(const float* __restrict__ W_lh, const float* __restrict__ b_lh,
           const float* __restrict__ W_lc, const float* __restrict__ b_lc,
           unsigned char* __restrict__ ws) {
  __shared__ float gat[2048];
  const int b=(int)blockIdx.x, tid=(int)threadIdx.x;
  const int lane=tid&63, wave=tid>>6;
  const int lm=lane&15, lq8=(lane>>4)*8;
  const int cg=wave&3, kh=wave>>2;
  const int ct=8*((b>>3)&7)+(b&7);
  const int R0=(b>>6)*16;
  unsigned short* bfb=(unsigned short*)ws;
  float* f32b=(float*)(ws+F32BASE);
  if (ct >= 32) return;
  const float* Wf = (ct < 16) ? W_lh : W_lc;
  int jb = 64 * (ct & 15) + 16 * cg + lm;
  f32x4 acc = {};
  acc = mmKf<8>(bfb + O_ZB + (size_t)(R0 + lm) * LAT + kh * 256 + lq8,
                Wf + (size_t)jb * LAT + kh * 256 + lq8, acc);
  dumpw(gat, acc, kh, cg, lane);
  __syncthreads();
  int prow = tid >> 5, cp2 = 2 * (tid & 31);
  int j0 = 64 * (ct & 15) + cp2;
  size_t gi0 = (size_t)(R0 + prow) * HID + j0;
  if (ct < 16) {
    float v0 = ftanh(gs(gat, prow, cp2) + b_lh[j0]);
    float v1 = ftanh(gs(gat, prow, cp2 + 1) + b_lh[j0 + 1]);
    unsigned pk = packbf(v0, v1);
    *(unsigned*)(bfb + O_HZ + gi0) = pk;
    *(unsigned*)(bfb + O_H0F + gi0) = pk;
    *(unsigned*)(bfb + O_H1F + gi0) = pk;
  } else {
    float v0 = ftanh(gs(gat, prow, cp2) + b_lc[j0]);
    float v1 = ftanh(gs(gat, prow, cp2 + 1) + b_lc[j0 + 1]);
    *(unsigned*)(bfb + O_CZB + gi0) = packbf(v0, v1);
    float2 vv; vv.x = v0; vv.y = v1;
    *(float2*)(f32b + OF_CZ + gi0) = vv;
    *(float2*)(f32b + OF_C0F + gi0) = vv;
    *(float2*)(f32b + OF_C1F + gi0) = vv;
  }
}

// ---- prologue: Ghz / Gcz ----
__global__ __launch_bounds__(NTHR)
void k_phc(const float* __restrict__ Wg_h, const float* __restrict__ bg_h,
           const float* __restrict__ Wg_c, const float* __restrict__ bg_c,
           unsigned char* __restrict__ ws) {
  __shared__ float gat[2048];
  const int b=(int)blockIdx.x, tid=(int)threadIdx.x;
  const int lane=tid&63, wave=tid>>6;
  const int lm=lane&15, lq8=(lane>>4)*8;
  const int cg=wave&3, kh=wave>>2;
  const int ct=8*((b>>3)&7)+(b&7);
  const int R0=(b>>6)*16;
  unsigned short* bfb=(unsigned short*)ws;
  float* f32b=(float*)(ws+F32BASE);
  if (ct >= 32) return;
  const unsigned short* A = (ct < 16) ? bfb + O_HZ : bfb + O_CZB;
  const float* Wf = (ct < 16) ? Wg_h : Wg_c;
  int jb = 64 * (ct & 15) + 16 * cg + lm;
  f32x4 acc = {};
  acc = mmKf<16>(A + (size_t)(R0 + lm) * HID + kh * 512 + lq8,
                 Wf + (size_t)jb * (2 * HID) + HID + kh * 512 + lq8, acc);
  dumpw(gat, acc, kh, cg, lane);
  __syncthreads();
  int prow = tid >> 5, cp2 = 2 * (tid & 31);
  int j0 = 64 * (ct & 15) + cp2;
  const float* bg = (ct < 16) ? bg_h : bg_c;
  float* G = (ct < 16) ? f32b + OF_GHZ : f32b + OF_GCZ;
  float2 vv;
  vv.x = gs(gat, prow, cp2) + bg[j0];
  vv.y = gs(gat, prow, cp2 + 1) + bg[j0 + 1];
  *(float2*)(G + (size_t)(R0 + prow) * HID + j0) = vv;
}

// ======== steady-state: per-wave 16x16 full-K tiles, DMA-staged weights ========

// ---- A: gates0 = x@W_ih0^T + h0f@W_hh0^T -> h0n, c0n ----
__global__ __launch_bounds__(NT2)
void k_p1(const float* __restrict__ bih, const float* __restrict__ bhh,
          unsigned char* __restrict__ ws) {
  __shared__ float gat[4 * 272];
  __shared__ unsigned short wlds[16 * 1032];   // W_hh0 tile, row stride 2064B
  unsigned short* bfb = (unsigned short*)ws;
  float* f32b = (float*)(ws + F32BASE);
  const int b = (int)blockIdx.x, tid = (int)threadIdx.x;
  const int lane = tid & 63, wave = tid >> 6;
  const int lm = lane & 15, lq8 = (lane >> 4) * 8;
  const int cg = b & 255, h = b >> 8;
  const int R0 = (4 * h + wave) * 16;
  const int U0 = 4 * cg;
  // async-stage 16 rows x 2KB of W_hh0 as 32 x 1KB DMAs (deep MLP, no VGPR consumers)
  for (int idx = wave; idx < 32; idx += 4) {
    int r = idx >> 1, c = idx & 1;
    int grow = (r >> 2) * HID + U0 + (r & 3);
    GLL16(bfb + O_WHH0 + (size_t)grow * HID + c * 512 + lane * 8,
          wlds + r * 1032 + c * 512);
  }
  const int erow = lane >> 2, edu = lane & 3;
  const int eu = U0 + edu;
  const size_t egix = (size_t)(R0 + erow) * HID + eu;
  float cprev = (f32b + OF_C0F)[egix];
  float ebi = bih[eu] + bhh[eu];
  float ebf = bih[HID + eu] + bhh[HID + eu];
  float ebg = bih[2 * HID + eu] + bhh[2 * HID + eu];
  float ebo = bih[3 * HID + eu] + bhh[3 * HID + eu];
  f32x4 acc = {};
  const int wrow = (lm >> 2) * HID + U0 + (lm & 3);
  acc = mmK<8>(bfb + O_XB + (size_t)(R0 + lm) * INP + lq8,
               bfb + O_WIH0 + (size_t)wrow * INP + lq8, acc);
  asm volatile("s_waitcnt vmcnt(0)" ::: "memory");
  __syncthreads();
  acc = mmK<32>(bfb + O_H0F + (size_t)(R0 + lm) * HID + lq8,
                wlds + lm * 1032 + lq8, acc);

  float* g = gat + wave * 272;                 // wave-private
  const int wr = (lane >> 4) * 4;
#pragma unroll
  for (int j = 0; j < 4; ++j) g[(wr + j) * 17 + lm] = acc[j];
  float s_i = g[erow * 17 + edu];
  float s_f = g[erow * 17 + 4 + edu];
  float s_g = g[erow * 17 + 8 + edu];
  float s_o = g[erow * 17 + 12 + edu];
  float gi_ = sigm(s_i + ebi), gf_ = sigm(s_f + ebf);
  float gg_ = ftanh(s_g + ebg), go_ = sigm(s_o + ebo);
  float cn = gf_ * cprev + gi_ * gg_;
  (bfb + O_H0N)[egix] = f2bf(go_ * ftanh(cn));
  (f32b + OF_C0N)[egix] = cn;
  (bfb + O_C0NB)[egix] = f2bf(cn);
}

// ---- B: gates1 = h0n@W_ih1^T + h1f@W_hh1^T -> h1n, c1n ----
__global__ __launch_bounds__(NT2)
void k_p2(const float* __restrict__ bih, const float* __restrict__ bhh,
          unsigned char* __restrict__ ws) {
  __shared__ float gat[4 * 272];
  __shared__ unsigned short wlds[32 * 1032];   // W_ih1 + W_hh1 tiles (66KB -> 2 blk/CU)
  unsigned short* bfb = (unsigned short*)ws;
  float* f32b = (float*)(ws + F32BASE);
  const int b = (int)blockIdx.x, tid = (int)threadIdx.x;
  const int lane = tid & 63, wave = tid >> 6;
  const int lm = lane & 15, lq8 = (lane >> 4) * 8;
  const int cg = b & 255, h = b >> 8;
  const int R0 = (4 * h + wave) * 16;
  const int U0 = 4 * cg;
  for (int idx = wave; idx < 64; idx += 4) {
    int r = idx >> 1, c = idx & 1;
    int rr = r & 15;
    int grow = (rr >> 2) * HID + U0 + (rr & 3);
    const unsigned short* gsrc = bfb + ((r < 16) ? O_WIH1 : O_WHH1)
                               + (size_t)grow * HID + c * 512 + lane * 8;
    GLL16(gsrc, wlds + r * 1032 + c * 512);
  }
  const int erow = lane >> 2, edu = lane & 3;
  const int eu = U0 + edu;
  const size_t egix = (size_t)(R0 + erow) * HID + eu;
  float cprev = (f32b + OF_C1F)[egix];
  float ebi = bih[eu] + bhh[eu];
  float ebf = bih[HID + eu] + bhh[HID + eu];
  float ebg = bih[2 * HID + eu] + bhh[2 * HID + eu];
  float ebo = bih[3 * HID + eu] + bhh[3 * HID + eu];
  asm volatile("s_waitcnt vmcnt(0)" ::: "memory");
  __syncthreads();
  f32x4 acc = {};
  acc = mmK<32>(bfb + O_H0N + (size_t)(R0 + lm) * HID + lq8, wlds + lm * 1032 + lq8, acc);
  acc = mmK<32>(bfb + O_H1F + (size_t)(R0 + lm) * HID + lq8, wlds + (16 + lm) * 1032 + lq8, acc);

  float* g = gat + wave * 272;
  const int wr = (lane >> 4) * 4;
#pragma unroll
  for (int j = 0; j < 4; ++j) g[(wr + j) * 17 + lm] = acc[j];
  float s_i = g[erow * 17 + edu];
  float s_f = g[erow * 17 + 4 + edu];
  float s_g = g[erow * 17 + 8 + edu];
  float s_o = g[erow * 17 + 12 + edu];
  float gi_ = sigm(s_i + ebi), gf_ = sigm(s_f + ebf);
  float gg_ = ftanh(s_g + ebg), go_ = sigm(s_o + ebo);
  float cn = gf_ * cprev + gi_ * gg_;
  (bfb + O_H1N)[egix] = f2bf(go_ * ftanh(cn));
  (f32b + OF_C1N)[egix] = cn;
  (bfb + O_C1NB)[egix] = f2bf(cn);
}

// ---- C': fc1 | gh0 | gh1 | gc0 | gc1 (WGH/WGC each read once) ----
__global__ __launch_bounds__(NT2)
void k_p3(const float* __restrict__ bfc1, unsigned char* __restrict__ ws) {
  __shared__ unsigned short wlds[16 * 1032];
  unsigned short* bfb = (unsigned short*)ws;
  float* f32b = (float*)(ws + F32BASE);
  const int b = (int)blockIdx.x, tid = (int)threadIdx.x;
  const int lane = tid & 63, wave = tid >> 6;
  const int lm = lane & 15, lq8 = (lane >> 4) * 8;
  const int h = b / 320, t_ = b - 320 * h;
  const int role = t_ >> 6;                  // 0 fc1, 1 gh0, 2 gh1, 3 gc0, 4 gc1
  const int c0 = (t_ & 63) * 16;
  const int R0 = (4 * h + wave) * 16;
  const unsigned short* A = (role == 0) ? bfb + O_H1N
                          : (role == 1) ? bfb + O_H0N
                          : (role == 2) ? bfb + O_H1N
                          : (role == 3) ? bfb + O_C0NB : bfb + O_C1NB;
  const unsigned short* W = (role == 0) ? bfb + O_WFC1
                          : (role <= 2) ? bfb + O_WGH : bfb + O_WGC;
  for (int idx = wave; idx < 32; idx += 4) {
    int r = idx >> 1, c = idx & 1;
    GLL16(W + (size_t)(c0 + r) * HID + c * 512 + lane * 8,
          wlds + r * 1032 + c * 512);
  }
  asm volatile("s_waitcnt vmcnt(0)" ::: "memory");
  __syncthreads();
  f32x4 acc = {};
  acc = mmK<32>(A + (size_t)(R0 + lm) * HID + lq8, wlds + lm * 1032 + lq8, acc);
  const int wr = (lane >> 4) * 4;
#pragma unroll
  for (int jj = 0; jj < 4; ++jj) {
    const int row = wr + jj;
    const size_t gi0 = (size_t)(R0 + row) * HID + c0 + lm;
    float s = acc[jj];
    if (role == 0) {
      float v = s + bfc1[c0 + lm];
      (bfb + O_RB)[gi0] = f2bf(v > 0.f ? v : 0.f);
    } else if (role == 1 || role == 2) {
      const unsigned short* Hn = (role == 1) ? bfb + O_H0N : bfb + O_H1N;
      unsigned short* Hf = (role == 1) ? bfb + O_H0F : bfb + O_H1F;
      float g0 = sigm(s + (f32b + OF_GHZ)[gi0]);
      float n0 = g0 * bf2f(Hn[gi0]) + (1.f - g0) * bf2f((bfb + O_HZ)[gi0]);
      Hf[gi0] = f2bf(n0);
    } else {
      const float* Cn = (role == 3) ? f32b + OF_C0N : f32b + OF_C1N;
      float* Cf = (role == 3) ? f32b + OF_C0F : f32b + OF_C1F;
      float g0 = sigm(s + (f32b + OF_GCZ)[gi0]);
      Cf[gi0] = g0 * Cn[gi0] + (1.f - g0) * (f32b + OF_CZ)[gi0];
    }
  }
}

// ---- D: fc2(Rb)->y_t, x_{t+1} (tiny, 32 blocks) ----
__global__ __launch_bounds__(NT2)
void k_p4(const float* __restrict__ bfc2, float* __restrict__ out, int t, int T,
          unsigned char* __restrict__ ws) {
  __shared__ unsigned short wlds[16 * 1032];
  unsigned short* bfb = (unsigned short*)ws;
  const int b = (int)blockIdx.x, tid = (int)threadIdx.x;
  const int lane = tid & 63, wave = tid >> 6;
  const int lm = lane & 15, lq8 = (lane >> 4) * 8;
  const int h = b >> 4, ct = b & 15;
  const int R0 = (4 * h + wave) * 16;
  const int c0 = ct * 16;
  for (int idx = wave; idx < 32; idx += 4) {
    int r = idx >> 1, c = idx & 1;
    GLL16(bfb + O_WFC2 + (size_t)(c0 + r) * HID + c * 512 + lane * 8,
          wlds + r * 1032 + c * 512);
  }
  asm volatile("s_waitcnt vmcnt(0)" ::: "memory");
  __syncthreads();
  f32x4 acc = {};
  acc = mmK<32>(bfb + O_RB + (size_t)(R0 + lm) * HID + lq8, wlds + lm * 1032 + lq8, acc);
  const int wr = (lane >> 4) * 4;
#pragma unroll
  for (int jj = 0; jj < 4; ++jj) {
    const int row = wr + jj;
    float v = acc[jj] + bfc2[c0 + lm];
    out[((size_t)(R0 + row) * T + t) * OUTD + c0 + lm] = v;
    (bfb + O_XB)[(size_t)(R0 + row) * INP + c0 + lm] = f2bf(v);
  }
}

extern "C" void kernel_launch(void* const* d_in, const int* in_sizes, int n_in,
                              void* d_out, int out_size, void* d_ws, size_t ws_size,
                              hipStream_t stream) {
  unsigned char* ws = (unsigned char*)d_ws;
  const float* z     = (const float*)d_in[0];
  const float* stok  = (const float*)d_in[2];
  const float* W_ih0 = (const float*)d_in[3];
  const float* W_hh0 = (const float*)d_in[4];
  const float* b_ih0 = (const float*)d_in[5];
  const float* b_hh0 = (const float*)d_in[6];
  const float* W_ih1 = (const float*)d_in[7];
  const float* W_hh1 = (const float*)d_in[8];
  const float* b_ih1 = (const float*)d_in[9];
  const float* b_hh1 = (const float*)d_in[10];
  const float* W_lh  = (const float*)d_in[11];
  const float* b_lh  = (const float*)d_in[12];
  const float* W_lc  = (const float*)d_in[13];
  const float* b_lc  = (const float*)d_in[14];
  const float* W_fc1 = (const float*)d_in[15];
  const float* b_fc1 = (const float*)d_in[16];
  const float* W_fc2 = (const float*)d_in[17];
  const float* b_fc2 = (const float*)d_in[18];
  const float* Wg_h  = (const float*)d_in[19];
  const float* bg_h  = (const float*)d_in[20];
  const float* Wg_c  = (const float*)d_in[21];
  const float* bg_c  = (const float*)d_in[22];

  const int T = out_size / (BSZ * OUTD);

  k_conv<<<dim3(2048), dim3(256), 0, stream>>>(z, stok, W_ih0, W_hh0, W_ih1, W_hh1,
                                               W_fc1, W_fc2, Wg_h, Wg_c, ws);
  k_phb<<<dim3(512), dim3(NTHR), 0, stream>>>(W_lh, b_lh, W_lc, b_lc, ws);
  k_phc<<<dim3(512), dim3(NTHR), 0, stream>>>(Wg_h, bg_h, Wg_c, bg_c, ws);

  for (int t = 0; t < T; ++t) {
    k_p1<<<dim3(512), dim3(NT2), 0, stream>>>(b_ih0, b_hh0, ws);
    k_p2<<<dim3(512), dim3(NT2), 0, stream>>>(b_ih1, b_hh1, ws);
    k_p3<<<dim3(640), dim3(NT2), 0, stream>>>(b_fc1, ws);
    k_p4<<<dim3(32), dim3(NT2), 0, stream>>>(b_fc2, (float*)d_out, t, T, ws);
  }
}